// Round 4
// baseline (96.575 us; speedup 1.0000x reference)
//
#include <hip/hip_runtime.h>

#define N_TOKENS 8192
#define D_MODEL  1024
#define E_NUM    8
#define SCAN_THREADS 1024
#define TPT (N_TOKENS / SCAN_THREADS)   // 8 tokens per thread
#define N_WAVES (SCAN_THREADS / 64)     // 16

typedef unsigned long long u64;
typedef float f4 __attribute__((ext_vector_type(4)));

// ---------------------------------------------------------------------------
// Kernel 1: routing decision + per-expert prefix-sum + FORWARD map.
// loc[t][e] = slot of token t in expert e, or -1 if inactive.
// Single block of 1024 threads; thread t owns tokens [t*8, t*8+8).
// Per-expert counts packed as 16-bit fields in two u64s (loads <= 8192 fits).
// ---------------------------------------------------------------------------
__global__ __launch_bounds__(SCAN_THREADS)
void route_kernel(const float* __restrict__ gates,
                  int* __restrict__ loc,       // [N_TOKENS * E_NUM] forward map
                  int* __restrict__ loads_i,   // [E_NUM]
                  float* __restrict__ loads_f) // d_out tail
{
    const int tid  = threadIdx.x;
    const int lane = tid & 63;
    const int wid  = tid >> 6;          // 0..15
    __shared__ u64 wt0[N_WAVES];
    __shared__ u64 wt1[N_WAVES];

    unsigned char masks[TPT];
    u64 c0 = 0ull, c1 = 0ull;           // experts 0..3 / 4..7, 16-bit fields
    const int t0 = tid * TPT;

#pragma unroll
    for (int k = 0; k < TPT; ++k) {
        const float4 g0 = *reinterpret_cast<const float4*>(gates + (size_t)(t0 + k) * E_NUM);
        const float4 g1 = *reinterpret_cast<const float4*>(gates + (size_t)(t0 + k) * E_NUM + 4);
        unsigned m = 0;
        m |= (g0.x > 0.0f) ? 1u   : 0u;
        m |= (g0.y > 0.0f) ? 2u   : 0u;
        m |= (g0.z > 0.0f) ? 4u   : 0u;
        m |= (g0.w > 0.0f) ? 8u   : 0u;
        m |= (g1.x > 0.0f) ? 16u  : 0u;
        m |= (g1.y > 0.0f) ? 32u  : 0u;
        m |= (g1.z > 0.0f) ? 64u  : 0u;
        m |= (g1.w > 0.0f) ? 128u : 0u;
        if (m == 0u) m = 1u;            // residual -> expert 0
        masks[k] = (unsigned char)m;
#pragma unroll
        for (int e = 0; e < 4; ++e) {
            c0 += (u64)((m >> e) & 1u) << (16 * e);
            c1 += (u64)((m >> (e + 4)) & 1u) << (16 * e);
        }
    }

    // Wave-level inclusive scan of packed counts (64 lanes, 6 shuffle steps).
    u64 v0 = c0, v1 = c1;
#pragma unroll
    for (int off = 1; off < 64; off <<= 1) {
        const u64 a0 = (u64)__shfl_up((long long)v0, off, 64);
        const u64 a1 = (u64)__shfl_up((long long)v1, off, 64);
        if (lane >= off) { v0 += a0; v1 += a1; }
    }
    if (lane == 63) { wt0[wid] = v0; wt1[wid] = v1; }
    __syncthreads();

    // Cross-wave exclusive prefix (16 u64 adds, wave-uniform).
    u64 p0 = 0ull, p1 = 0ull;
#pragma unroll
    for (int w = 0; w < N_WAVES; ++w) {
        if (w < wid) { p0 += wt0[w]; p1 += wt1[w]; }
    }

    // Exclusive per-expert base offsets for this thread.
    const u64 e0 = p0 + v0 - c0, e1 = p1 + v1 - c1;
    int offs[E_NUM];
#pragma unroll
    for (int e = 0; e < 4; ++e) {
        offs[e]     = (int)((e0 >> (16 * e)) & 0xFFFFull);
        offs[e + 4] = (int)((e1 >> (16 * e)) & 0xFFFFull);
    }

    // Forward map: thread writes 64 consecutive ints (256 B contiguous).
#pragma unroll
    for (int k = 0; k < TPT; ++k) {
        const unsigned m = masks[k];
        const int token = t0 + k;
#pragma unroll
        for (int e = 0; e < E_NUM; ++e) {
            if (m & (1u << e)) {
                loc[token * E_NUM + e] = offs[e];
                offs[e]++;
            } else {
                loc[token * E_NUM + e] = -1;
            }
        }
    }

    // Thread 0 computes total loads from the wave totals.
    if (tid == 0) {
        u64 tot0 = 0ull, tot1 = 0ull;
#pragma unroll
        for (int w = 0; w < N_WAVES; ++w) { tot0 += wt0[w]; tot1 += wt1[w]; }
#pragma unroll
        for (int e = 0; e < 4; ++e) {
            const int l0 = (int)((tot0 >> (16 * e)) & 0xFFFFull);
            const int l1 = (int)((tot1 >> (16 * e)) & 0xFFFFull);
            loads_i[e]     = l0;
            loads_i[e + 4] = l1;
            loads_f[e]     = (float)l0;
            loads_f[e + 4] = (float)l1;
        }
    }
}

// ---------------------------------------------------------------------------
// Kernel 2: combined data-scatter + zero-fill, 2*N_TOKENS blocks.
//  blocks [0, N):   token-major — read token row ONCE (4 KB, coalesced),
//                   write to each active expert slot (~4.2 rows).
//  blocks [N, 2N):  slot r = bid - N; for each e with r >= loads[e],
//                   stream zeros into out[e][r] (pure write).
// Data slots and zero slots are disjoint and together cover all E*N rows.
// ---------------------------------------------------------------------------
__global__ __launch_bounds__(256)
void scatter_kernel(const float* __restrict__ in_flow,
                    const int* __restrict__ loc,
                    const int* __restrict__ loads_i,
                    float* __restrict__ out)
{
    const int tid = threadIdx.x;
    const int bid = blockIdx.x;

    if (bid < N_TOKENS) {
        // --- data path: one token, read once, write to active experts ---
        const int t = bid;
        const f4 val = *reinterpret_cast<const f4*>(
            in_flow + (size_t)t * D_MODEL + (size_t)tid * 4);
#pragma unroll
        for (int e = 0; e < E_NUM; ++e) {
            const int r = loc[t * E_NUM + e];       // broadcast load
            if (r >= 0) {
                *reinterpret_cast<f4*>(
                    out + ((size_t)e * N_TOKENS + r) * D_MODEL + (size_t)tid * 4) = val;
            }
        }
    } else {
        // --- zero path: slot r across all experts ---
        const int r = bid - N_TOKENS;
        const f4 z = (f4)(0.0f);
#pragma unroll
        for (int e = 0; e < E_NUM; ++e) {
            if (r >= loads_i[e]) {
                *reinterpret_cast<f4*>(
                    out + ((size_t)e * N_TOKENS + r) * D_MODEL + (size_t)tid * 4) = z;
            }
        }
    }
}

extern "C" void kernel_launch(void* const* d_in, const int* in_sizes, int n_in,
                              void* d_out, int out_size, void* d_ws, size_t ws_size,
                              hipStream_t stream) {
    const float* in_flow = (const float*)d_in[0];   // (8192, 1024) f32
    const float* gates   = (const float*)d_in[1];   // (8192, 8) f32
    float* out = (float*)d_out;                     // 8*8192*1024 + 8 floats

    int* loc     = (int*)d_ws;                      // N*E ints = 256 KB
    int* loads_i = loc + N_TOKENS * E_NUM;          // 8 ints
    float* loads_f = out + (size_t)E_NUM * N_TOKENS * D_MODEL;

    route_kernel<<<1, SCAN_THREADS, 0, stream>>>(gates, loc, loads_i, loads_f);

    scatter_kernel<<<2 * N_TOKENS, 256, 0, stream>>>(in_flow, loc, loads_i, out);
}

// Round 5
// 80.334 us; speedup vs baseline: 1.2022x; 1.2022x over previous
//
#include <hip/hip_runtime.h>

#define N_TOKENS 8192
#define D_MODEL  1024
#define E_NUM    8
#define SCAN_THREADS 1024
#define TPT (N_TOKENS / SCAN_THREADS)   // 8 tokens per thread
#define N_WAVES (SCAN_THREADS / 64)     // 16
#define RPB 8                           // rows per scatter block (divides 8192)

typedef unsigned long long u64;
typedef float f4 __attribute__((ext_vector_type(4)));

// ---------------------------------------------------------------------------
// Kernel 1: routing decision + per-expert prefix-sum + inverse map.
// Single block of 1024 threads; thread t owns tokens [t*8, t*8+8).
// Per-expert counts packed as 16-bit fields in two u64s (loads <= 8192 fits).
// Scan = wave-level shfl_up scan (6 steps) + cross-wave partials (1 barrier).
// ---------------------------------------------------------------------------
__global__ __launch_bounds__(SCAN_THREADS)
void route_kernel(const float* __restrict__ gates,
                  int* __restrict__ rows,      // [E_NUM * N_TOKENS] inverse map
                  int* __restrict__ loads_i,   // [E_NUM]
                  float* __restrict__ loads_f) // d_out tail
{
    const int tid  = threadIdx.x;
    const int lane = tid & 63;
    const int wid  = tid >> 6;          // 0..15
    __shared__ u64 wt0[N_WAVES];
    __shared__ u64 wt1[N_WAVES];

    unsigned char masks[TPT];
    u64 c0 = 0ull, c1 = 0ull;           // experts 0..3 / 4..7, 16-bit fields
    const int t0 = tid * TPT;

#pragma unroll
    for (int k = 0; k < TPT; ++k) {
        const float4 g0 = *reinterpret_cast<const float4*>(gates + (size_t)(t0 + k) * E_NUM);
        const float4 g1 = *reinterpret_cast<const float4*>(gates + (size_t)(t0 + k) * E_NUM + 4);
        unsigned m = 0;
        m |= (g0.x > 0.0f) ? 1u   : 0u;
        m |= (g0.y > 0.0f) ? 2u   : 0u;
        m |= (g0.z > 0.0f) ? 4u   : 0u;
        m |= (g0.w > 0.0f) ? 8u   : 0u;
        m |= (g1.x > 0.0f) ? 16u  : 0u;
        m |= (g1.y > 0.0f) ? 32u  : 0u;
        m |= (g1.z > 0.0f) ? 64u  : 0u;
        m |= (g1.w > 0.0f) ? 128u : 0u;
        if (m == 0u) m = 1u;            // residual -> expert 0
        masks[k] = (unsigned char)m;
#pragma unroll
        for (int e = 0; e < 4; ++e) {
            c0 += (u64)((m >> e) & 1u) << (16 * e);
            c1 += (u64)((m >> (e + 4)) & 1u) << (16 * e);
        }
    }

    // Wave-level inclusive scan of packed counts (64 lanes, 6 shuffle steps).
    u64 v0 = c0, v1 = c1;
#pragma unroll
    for (int off = 1; off < 64; off <<= 1) {
        const u64 a0 = (u64)__shfl_up((long long)v0, off, 64);
        const u64 a1 = (u64)__shfl_up((long long)v1, off, 64);
        if (lane >= off) { v0 += a0; v1 += a1; }
    }
    if (lane == 63) { wt0[wid] = v0; wt1[wid] = v1; }
    __syncthreads();

    // Cross-wave exclusive prefix (16 u64 adds, wave-uniform).
    u64 p0 = 0ull, p1 = 0ull;
#pragma unroll
    for (int w = 0; w < N_WAVES; ++w) {
        if (w < wid) { p0 += wt0[w]; p1 += wt1[w]; }
    }

    // Exclusive per-expert base offsets for this thread.
    const u64 e0 = p0 + v0 - c0, e1 = p1 + v1 - c1;
    int offs[E_NUM];
#pragma unroll
    for (int e = 0; e < 4; ++e) {
        offs[e]     = (int)((e0 >> (16 * e)) & 0xFFFFull);
        offs[e + 4] = (int)((e1 >> (16 * e)) & 0xFFFFull);
    }

    // Scatter inverse map: rows[e][r] = token index (ascending token order).
#pragma unroll
    for (int k = 0; k < TPT; ++k) {
        const unsigned m = masks[k];
        const int token = t0 + k;
#pragma unroll
        for (int e = 0; e < E_NUM; ++e) {
            if (m & (1u << e)) {
                rows[e * N_TOKENS + offs[e]] = token;
                offs[e]++;
            }
        }
    }

    // Thread 0 computes total loads from the wave totals.
    if (tid == 0) {
        u64 tot0 = 0ull, tot1 = 0ull;
#pragma unroll
        for (int w = 0; w < N_WAVES; ++w) { tot0 += wt0[w]; tot1 += wt1[w]; }
#pragma unroll
        for (int e = 0; e < 4; ++e) {
            const int l0 = (int)((tot0 >> (16 * e)) & 0xFFFFull);
            const int l1 = (int)((tot1 >> (16 * e)) & 0xFFFFull);
            loads_i[e]     = l0;
            loads_i[e + 4] = l1;
            loads_f[e]     = (float)l0;
            loads_f[e + 4] = (float)l1;
        }
    }
}

// ---------------------------------------------------------------------------
// Kernel 2: e-major output sweep, 8 consecutive rows per block (32 KB
// contiguous store region -> good DRAM page locality; rows within an expert
// are ascending-token -> reads nearly sequential too). All 8 gather loads
// issued before the 8 nontemporal stores (MLP). Blocks never straddle an
// expert boundary, so loads[e] is one scalar load per block.
// ---------------------------------------------------------------------------
__global__ __launch_bounds__(256)
void scatter_kernel(const float* __restrict__ in_flow,
                    const int* __restrict__ rows,
                    const int* __restrict__ loads_i,
                    float* __restrict__ out)
{
    const int tid = threadIdx.x;
    const int bid = blockIdx.x;
    const int e   = bid >> 10;                  // 1024 blocks per expert
    const int r0  = (bid & 1023) * RPB;
    const int load_e = loads_i[e];              // uniform -> scalar load

    const int* rp = rows + e * N_TOKENS + r0;
    int trow[RPB];
#pragma unroll
    for (int j = 0; j < RPB; ++j) trow[j] = rp[j];  // uniform broadcast loads

    f4 vals[RPB];
#pragma unroll
    for (int j = 0; j < RPB; ++j) {
        if (r0 + j < load_e) {
            vals[j] = *reinterpret_cast<const f4*>(
                in_flow + (size_t)trow[j] * D_MODEL + (size_t)tid * 4);
        } else {
            vals[j] = (f4)(0.0f);
        }
    }

    float* base = out + ((size_t)e * N_TOKENS + r0) * D_MODEL + (size_t)tid * 4;
#pragma unroll
    for (int j = 0; j < RPB; ++j) {
        __builtin_nontemporal_store(
            vals[j], reinterpret_cast<f4*>(base + (size_t)j * D_MODEL));
    }
}

extern "C" void kernel_launch(void* const* d_in, const int* in_sizes, int n_in,
                              void* d_out, int out_size, void* d_ws, size_t ws_size,
                              hipStream_t stream) {
    const float* in_flow = (const float*)d_in[0];   // (8192, 1024) f32
    const float* gates   = (const float*)d_in[1];   // (8192, 8) f32
    float* out = (float*)d_out;                     // 8*8192*1024 + 8 floats

    int* rows    = (int*)d_ws;                      // E*N ints = 256 KB
    int* loads_i = rows + E_NUM * N_TOKENS;         // 8 ints
    float* loads_f = out + (size_t)E_NUM * N_TOKENS * D_MODEL;

    route_kernel<<<1, SCAN_THREADS, 0, stream>>>(gates, rows, loads_i, loads_f);

    const int n_blocks = E_NUM * N_TOKENS / RPB;    // 8192
    scatter_kernel<<<n_blocks, 256, 0, stream>>>(in_flow, rows, loads_i, out);
}